// Round 7
// baseline (63.818 us; speedup 1.0000x reference)
//
#include <hip/hip_runtime.h>

// Problem constants (fixed by the reference's setup_inputs):
//   B=128 batches, S=32768 sequence, P=65536 path steps.
#define NB 128
#define NS 32768
#define NP 65536
#define POS_W 5.0f

constexpr int MASK_WORDS = (NB * NS) / 32;   // 131072 words = 512 KB per mask plane
constexpr int WPB        = NS / 32;          // 1024 mask words per batch (4 KB)
constexpr int LOSS_BLOCKS = 1024;
constexpr double FXSCALE = 4294967296.0;     // 2^32 fixed-point scale for final sum

// ws layout:
//   [0, MASK_WORDS*4)                     : global targets bitmap (tbits)
//   [MASK_WORDS*4, +QPB*MASK_WORDS*4)     : QPB partial gt-mask planes
//   [after planes, 16 B]                  : {u64 fixed-point acc, u32 block counter}

// ---------------------------------------------------------------------------
// One-shot: targets (16 MB int32) -> 512 KB bitmap, via per-wave ballot.
__global__ __launch_bounds__(256)
void tbit_kernel(const int* __restrict__ targets, unsigned int* __restrict__ tb) {
    constexpr int NSEG = NB * NS / 64;
    const int lane = threadIdx.x & 63;
    const int wid  = (blockIdx.x * blockDim.x + threadIdx.x) >> 6;
    const int nw   = (gridDim.x * blockDim.x) >> 6;
    for (int s = wid; s < NSEG; s += nw) {
        const unsigned long long m = __ballot(targets[(size_t)s * 64 + lane] != 0);
        if (lane == 0)       tb[s * 2]     = (unsigned int)m;
        else if (lane == 32) tb[s * 2 + 1] = (unsigned int)(m >> 32);
    }
}

// ---------------------------------------------------------------------------
// One block = (batch b, plane q), 512 threads. Lane-consecutive (coalesced)
// int4 loads, ALL iterations hoisted into registers (deep MLP). prev-pj via
// shfl; per-wave boundary values prefetched by lanes 0..NIT-1 before the loop
// (no divergent loads inside). Random accesses stay in LDS (ds_or atomics).
template <int QPB>
__global__ __launch_bounds__(512)
void gt_kernel(const int* __restrict__ pw, const unsigned int* __restrict__ tbits_g,
               unsigned int* __restrict__ pmask) {
    __shared__ unsigned int tbits[WPB];   // 4 KB: targets[b] as bits
    __shared__ unsigned int gbits[WPB];   // 4 KB: this block's gt-bit plane

    // Layout detect (uniform scalar): int64 -> hi word of last elem == 0.
    const int is64 = (pw[2 * (size_t)NP - 1] == 0);

    const int q    = blockIdx.x;
    const int b    = blockIdx.y;
    const int tid  = threadIdx.x;         // 0..511
    const int lane = tid & 63;
    const int wbase = tid & ~63;          // wave's base tid

    tbits[tid]       = tbits_g[(size_t)b * WPB + tid];
    tbits[tid + 512] = tbits_g[(size_t)b * WPB + tid + 512];
    gbits[tid]       = 0u;
    gbits[tid + 512] = 0u;
    __syncthreads();

    constexpr int STEPS = NP / QPB;              // steps per block (8192 @ QPB=8)
    const int    k0    = q * STEPS;              // batch-local base step
    const size_t sbase = (size_t)b * NP + k0;    // global base step
    const int4*  p4    = (const int4*)pw;

    if (!is64) {
        // int32 layout: one int4 = 2 pairs; iter it: thread's steps are
        // k = k0 + (it*512 + tid)*2, k+1.  Lane-consecutive -> coalesced.
        constexpr int NIT = STEPS / 1024;        // 8 @ QPB=8
        constexpr int NCH = (NIT + 7) / 8;
        const size_t pb = sbase >> 1;
        // Per-wave boundary values: lane l holds prev-pj for iteration l.
        int bval = -1;
        if (lane < NIT) {
            const int kf = k0 + (lane * 512 + wbase) * 2;
            if (kf != 0) bval = pw[2 * ((size_t)b * NP + kf) - 1];
        }
        #pragma unroll
        for (int ch = 0; ch < NCH; ++ch) {
            int4 a[8];
            #pragma unroll
            for (int j = 0; j < 8; ++j) a[j] = p4[pb + (ch * 8 + j) * 512 + tid];
            #pragma unroll
            for (int j = 0; j < 8; ++j) {
                const int it = ch * 8 + j;
                const int pi0 = a[j].x, pj0 = a[j].y, pi1 = a[j].z, pj1 = a[j].w;
                const int pl = __shfl_up(pj1, 1);
                const int bv = __shfl(bval, it);
                const int prev = (lane == 0) ? bv : pl;
                const bool f0 = (pj0 != prev);
                const bool f1 = (pj1 != pj0);
                if (f0 && ((tbits[pj0 >> 5] >> (pj0 & 31)) & 1u))
                    atomicOr(&gbits[pi0 >> 5], 1u << (pi0 & 31));
                if (f1 && ((tbits[pj1 >> 5] >> (pj1 & 31)) & 1u))
                    atomicOr(&gbits[pi1 >> 5], 1u << (pi1 & 31));
            }
        }
    } else {
        // int64 layout: one int4 = 1 pair (pi=x, pj=z); iter it: step
        // k = k0 + it*512 + tid.  Lane-consecutive -> coalesced.
        constexpr int NIT = STEPS / 512;         // 16 @ QPB=8 (<=64 for QPB>=2)
        constexpr int NCH = (NIT + 7) / 8;
        int bval = -1;
        if (lane < NIT) {
            const int kf = k0 + lane * 512 + wbase;
            if (kf != 0) bval = pw[4 * ((size_t)b * NP + kf) - 2];
        }
        #pragma unroll
        for (int ch = 0; ch < NCH; ++ch) {
            int4 a[8];
            #pragma unroll
            for (int j = 0; j < 8; ++j) a[j] = p4[sbase + (ch * 8 + j) * 512 + tid];
            #pragma unroll
            for (int j = 0; j < 8; ++j) {
                const int it = ch * 8 + j;
                const int pi = a[j].x, pj = a[j].z;
                const int pl = __shfl_up(pj, 1);
                const int bv = __shfl(bval, it);
                const int prev = (lane == 0) ? bv : pl;
                if ((pj != prev) && ((tbits[pj >> 5] >> (pj & 31)) & 1u))
                    atomicOr(&gbits[pi >> 5], 1u << (pi & 31));
            }
        }
    }
    __syncthreads();

    unsigned int* dst = pmask + (size_t)q * MASK_WORDS + (size_t)b * WPB;
    dst[tid]       = gbits[tid];
    dst[tid + 512] = gbits[tid + 512];
}

// ---------------------------------------------------------------------------
// Streaming loss, float4-vectorized; gt bit = OR of QPB partial planes.
// Final reduction fused: per-block f32 sum -> u64 fixed-point atomicAdd
// (integer adds commute -> bit-deterministic); last block writes out[0].
template <int QPB>
__global__ __launch_bounds__(256)
void loss_kernel(const float* __restrict__ preds, const unsigned int* __restrict__ pmask,
                 unsigned long long* __restrict__ acc64, unsigned int* __restrict__ cnt,
                 float* __restrict__ out) {
    constexpr int N4 = (NB * NS) / 4;   // 1,048,576 float4s
    float acc = 0.f;
    const int stride = gridDim.x * blockDim.x;
    for (int idx = blockIdx.x * blockDim.x + threadIdx.x; idx < N4; idx += stride) {
        const float4 x = reinterpret_cast<const float4*>(preds)[idx];
        unsigned int mw = 0u;
        #pragma unroll
        for (int q = 0; q < QPB; ++q)
            mw |= pmask[(size_t)q * MASK_WORDS + (idx >> 3)];
        const unsigned int m = mw >> ((idx & 7) * 4);
        const float xs[4] = {x.x, x.y, x.z, x.w};
#pragma unroll
        for (int j = 0; j < 4; ++j) {
            const float v = xs[j];
            // stable softplus: sp(v) = log(1+exp(-|v|)) + max(v,0);  sp(-v) = sp(v) - v
            const float t = __logf(1.f + __expf(-fabsf(v)));
            const float sp_pos = t + fmaxf(v, 0.f);
            const float sp_neg = sp_pos - v;
            acc += ((m >> j) & 1u) ? POS_W * sp_neg : sp_pos;
        }
    }
    for (int off = 32; off; off >>= 1) acc += __shfl_down(acc, off);
    __shared__ float sacc[4];
    const int wave = threadIdx.x >> 6, lane = threadIdx.x & 63;
    if (lane == 0) sacc[wave] = acc;
    __syncthreads();
    if (threadIdx.x == 0) {
        float s = 0.f;
#pragma unroll
        for (int w = 0; w < 4; ++w) s += sacc[w];
        // deterministic fixed-point accumulate (loss >= 0)
        const unsigned long long fx = (unsigned long long)((double)s * FXSCALE + 0.5);
        atomicAdd(acc64, fx);
        __threadfence();
        const unsigned int c = atomicAdd(cnt, 1u);
        if (c == (unsigned int)gridDim.x - 1u) {
            __threadfence();
            const unsigned long long tot = atomicAdd(acc64, 0ull);
            out[0] = (float)((double)tot * (1.0 / FXSCALE) / ((double)NB * (double)NS));
        }
    }
}

// ---------------------------------------------------------------------------
extern "C" void kernel_launch(void* const* d_in, const int* in_sizes, int n_in,
                              void* d_out, int out_size, void* d_ws, size_t ws_size,
                              hipStream_t stream) {
    const float* preds   = (const float*)d_in[0];
    const int*   targets = (const int*)d_in[1];
    const int*   paths_w = (const int*)d_in[2];   // int32 words; layout auto-detected
    float*       out     = (float*)d_out;

    // Pick planes-per-batch by available workspace (deterministic for fixed ws).
    int qpb = 8;
    while (qpb > 2 &&
           ws_size < (size_t)(1 + qpb) * MASK_WORDS * 4 + 16)
        qpb >>= 1;

    unsigned int*        tbits_g = (unsigned int*)d_ws;
    unsigned int*        pmask   = tbits_g + MASK_WORDS;
    char*                tail    = (char*)d_ws + (size_t)(1 + qpb) * MASK_WORDS * 4;
    unsigned long long*  acc64   = (unsigned long long*)tail;
    unsigned int*        cnt     = (unsigned int*)(tail + 8);

    hipMemsetAsync(tail, 0, 16, stream);
    tbit_kernel<<<1024, 256, 0, stream>>>(targets, tbits_g);

    dim3 g1(qpb, NB);
    switch (qpb) {
        case 8:
            gt_kernel<8><<<g1, 512, 0, stream>>>(paths_w, tbits_g, pmask);
            loss_kernel<8><<<LOSS_BLOCKS, 256, 0, stream>>>(preds, pmask, acc64, cnt, out);
            break;
        case 4:
            gt_kernel<4><<<g1, 512, 0, stream>>>(paths_w, tbits_g, pmask);
            loss_kernel<4><<<LOSS_BLOCKS, 256, 0, stream>>>(preds, pmask, acc64, cnt, out);
            break;
        default:
            gt_kernel<2><<<g1, 512, 0, stream>>>(paths_w, tbits_g, pmask);
            loss_kernel<2><<<LOSS_BLOCKS, 256, 0, stream>>>(preds, pmask, acc64, cnt, out);
            break;
    }
}

// Round 8
// 59.819 us; speedup vs baseline: 1.0669x; 1.0669x over previous
//
#include <hip/hip_runtime.h>

// Problem constants (fixed by the reference's setup_inputs):
//   B=128 batches, S=32768 sequence, P=65536 path steps.
#define NB 128
#define NS 32768
#define NP 65536
#define POS_W 5.0f

constexpr int MASK_WORDS = (NB * NS) / 32;   // 131072 words = 512 KB per mask plane
constexpr int WPB        = NS / 32;          // 1024 mask words per batch (4 KB)
constexpr int LOSS_BLOCKS = 1024;
constexpr double FXSCALE = 4294967296.0;     // 2^32 fixed-point scale for final sum

// ws layout:
//   [0, MASK_WORDS*4)                     : global targets bitmap (tbits)
//   [MASK_WORDS*4, +QPB*MASK_WORDS*4)     : QPB partial gt-mask planes
//   [after planes, 16 B]                  : {u64 fixed-point acc, u32 block counter}

// ---------------------------------------------------------------------------
// One-shot: targets (16 MB int32) -> 512 KB bitmap, via per-wave ballot.
// Also zeroes the loss accumulator control words (no hipMemsetAsync: a tiny
// fill dispatch costs ~39 us per graph replay -- measured R7).
__global__ __launch_bounds__(256)
void tbit_kernel(const int* __restrict__ targets, unsigned int* __restrict__ tb,
                 unsigned long long* __restrict__ acc64, unsigned int* __restrict__ cnt) {
    if (blockIdx.x == 0 && threadIdx.x == 0) {
        acc64[0] = 0ull;
        cnt[0]   = 0u;
    }
    constexpr int NSEG = NB * NS / 64;
    const int lane = threadIdx.x & 63;
    const int wid  = (blockIdx.x * blockDim.x + threadIdx.x) >> 6;
    const int nw   = (gridDim.x * blockDim.x) >> 6;
    for (int s = wid; s < NSEG; s += nw) {
        const unsigned long long m = __ballot(targets[(size_t)s * 64 + lane] != 0);
        if (lane == 0)       tb[s * 2]     = (unsigned int)m;
        else if (lane == 32) tb[s * 2 + 1] = (unsigned int)(m >> 32);
    }
}

// ---------------------------------------------------------------------------
// One block = (batch b, plane q), 512 threads. Lane-consecutive (coalesced)
// int4 loads, ALL iterations hoisted into registers (deep MLP). prev-pj via
// shfl; per-wave boundary values prefetched by lanes 0..NIT-1 before the loop
// (no divergent loads inside). Random accesses stay in LDS (ds_or atomics).
template <int QPB>
__global__ __launch_bounds__(512)
void gt_kernel(const int* __restrict__ pw, const unsigned int* __restrict__ tbits_g,
               unsigned int* __restrict__ pmask) {
    __shared__ unsigned int tbits[WPB];   // 4 KB: targets[b] as bits
    __shared__ unsigned int gbits[WPB];   // 4 KB: this block's gt-bit plane

    // Layout detect (uniform scalar): int64 -> hi word of last elem == 0.
    const int is64 = (pw[2 * (size_t)NP - 1] == 0);

    const int q    = blockIdx.x;
    const int b    = blockIdx.y;
    const int tid  = threadIdx.x;         // 0..511
    const int lane = tid & 63;
    const int wbase = tid & ~63;          // wave's base tid

    tbits[tid]       = tbits_g[(size_t)b * WPB + tid];
    tbits[tid + 512] = tbits_g[(size_t)b * WPB + tid + 512];
    gbits[tid]       = 0u;
    gbits[tid + 512] = 0u;
    __syncthreads();

    constexpr int STEPS = NP / QPB;              // steps per block (8192 @ QPB=8)
    const int    k0    = q * STEPS;              // batch-local base step
    const size_t sbase = (size_t)b * NP + k0;    // global base step
    const int4*  p4    = (const int4*)pw;

    if (!is64) {
        // int32 layout: one int4 = 2 pairs; iter it: thread's steps are
        // k = k0 + (it*512 + tid)*2, k+1.  Lane-consecutive -> coalesced.
        constexpr int NIT = STEPS / 1024;        // 8 @ QPB=8
        constexpr int NCH = (NIT + 7) / 8;
        const size_t pb = sbase >> 1;
        // Per-wave boundary values: lane l holds prev-pj for iteration l.
        int bval = -1;
        if (lane < NIT) {
            const int kf = k0 + (lane * 512 + wbase) * 2;
            if (kf != 0) bval = pw[2 * ((size_t)b * NP + kf) - 1];
        }
        #pragma unroll
        for (int ch = 0; ch < NCH; ++ch) {
            int4 a[8];
            #pragma unroll
            for (int j = 0; j < 8; ++j) a[j] = p4[pb + (ch * 8 + j) * 512 + tid];
            #pragma unroll
            for (int j = 0; j < 8; ++j) {
                const int it = ch * 8 + j;
                const int pi0 = a[j].x, pj0 = a[j].y, pi1 = a[j].z, pj1 = a[j].w;
                const int pl = __shfl_up(pj1, 1);
                const int bv = __shfl(bval, it);
                const int prev = (lane == 0) ? bv : pl;
                const bool f0 = (pj0 != prev);
                const bool f1 = (pj1 != pj0);
                if (f0 && ((tbits[pj0 >> 5] >> (pj0 & 31)) & 1u))
                    atomicOr(&gbits[pi0 >> 5], 1u << (pi0 & 31));
                if (f1 && ((tbits[pj1 >> 5] >> (pj1 & 31)) & 1u))
                    atomicOr(&gbits[pi1 >> 5], 1u << (pi1 & 31));
            }
        }
    } else {
        // int64 layout: one int4 = 1 pair (pi=x, pj=z); iter it: step
        // k = k0 + it*512 + tid.  Lane-consecutive -> coalesced.
        constexpr int NIT = STEPS / 512;         // 16 @ QPB=8 (<=64 for QPB>=2)
        constexpr int NCH = (NIT + 7) / 8;
        int bval = -1;
        if (lane < NIT) {
            const int kf = k0 + lane * 512 + wbase;
            if (kf != 0) bval = pw[4 * ((size_t)b * NP + kf) - 2];
        }
        #pragma unroll
        for (int ch = 0; ch < NCH; ++ch) {
            int4 a[8];
            #pragma unroll
            for (int j = 0; j < 8; ++j) a[j] = p4[sbase + (ch * 8 + j) * 512 + tid];
            #pragma unroll
            for (int j = 0; j < 8; ++j) {
                const int it = ch * 8 + j;
                const int pi = a[j].x, pj = a[j].z;
                const int pl = __shfl_up(pj, 1);
                const int bv = __shfl(bval, it);
                const int prev = (lane == 0) ? bv : pl;
                if ((pj != prev) && ((tbits[pj >> 5] >> (pj & 31)) & 1u))
                    atomicOr(&gbits[pi >> 5], 1u << (pi & 31));
            }
        }
    }
    __syncthreads();

    unsigned int* dst = pmask + (size_t)q * MASK_WORDS + (size_t)b * WPB;
    dst[tid]       = gbits[tid];
    dst[tid + 512] = gbits[tid + 512];
}

// ---------------------------------------------------------------------------
// Streaming loss, float4-vectorized; gt bit = OR of QPB partial planes.
// Final reduction fused: per-block f32 sum -> u64 fixed-point atomicAdd
// (integer adds commute -> bit-deterministic); last block writes out[0].
template <int QPB>
__global__ __launch_bounds__(256)
void loss_kernel(const float* __restrict__ preds, const unsigned int* __restrict__ pmask,
                 unsigned long long* __restrict__ acc64, unsigned int* __restrict__ cnt,
                 float* __restrict__ out) {
    constexpr int N4 = (NB * NS) / 4;   // 1,048,576 float4s
    float acc = 0.f;
    const int stride = gridDim.x * blockDim.x;
    for (int idx = blockIdx.x * blockDim.x + threadIdx.x; idx < N4; idx += stride) {
        const float4 x = reinterpret_cast<const float4*>(preds)[idx];
        unsigned int mw = 0u;
        #pragma unroll
        for (int q = 0; q < QPB; ++q)
            mw |= pmask[(size_t)q * MASK_WORDS + (idx >> 3)];
        const unsigned int m = mw >> ((idx & 7) * 4);
        const float xs[4] = {x.x, x.y, x.z, x.w};
#pragma unroll
        for (int j = 0; j < 4; ++j) {
            const float v = xs[j];
            // stable softplus: sp(v) = log(1+exp(-|v|)) + max(v,0);  sp(-v) = sp(v) - v
            const float t = __logf(1.f + __expf(-fabsf(v)));
            const float sp_pos = t + fmaxf(v, 0.f);
            const float sp_neg = sp_pos - v;
            acc += ((m >> j) & 1u) ? POS_W * sp_neg : sp_pos;
        }
    }
    for (int off = 32; off; off >>= 1) acc += __shfl_down(acc, off);
    __shared__ float sacc[4];
    const int wave = threadIdx.x >> 6, lane = threadIdx.x & 63;
    if (lane == 0) sacc[wave] = acc;
    __syncthreads();
    if (threadIdx.x == 0) {
        float s = 0.f;
#pragma unroll
        for (int w = 0; w < 4; ++w) s += sacc[w];
        // deterministic fixed-point accumulate (loss >= 0)
        const unsigned long long fx = (unsigned long long)((double)s * FXSCALE + 0.5);
        atomicAdd(acc64, fx);
        __threadfence();
        const unsigned int c = atomicAdd(cnt, 1u);
        if (c == (unsigned int)gridDim.x - 1u) {
            __threadfence();
            const unsigned long long tot = atomicAdd(acc64, 0ull);
            out[0] = (float)((double)tot * (1.0 / FXSCALE) / ((double)NB * (double)NS));
        }
    }
}

// ---------------------------------------------------------------------------
extern "C" void kernel_launch(void* const* d_in, const int* in_sizes, int n_in,
                              void* d_out, int out_size, void* d_ws, size_t ws_size,
                              hipStream_t stream) {
    const float* preds   = (const float*)d_in[0];
    const int*   targets = (const int*)d_in[1];
    const int*   paths_w = (const int*)d_in[2];   // int32 words; layout auto-detected
    float*       out     = (float*)d_out;

    // Pick planes-per-batch by available workspace (deterministic for fixed ws).
    int qpb = 8;
    while (qpb > 2 &&
           ws_size < (size_t)(1 + qpb) * MASK_WORDS * 4 + 16)
        qpb >>= 1;

    unsigned int*        tbits_g = (unsigned int*)d_ws;
    unsigned int*        pmask   = tbits_g + MASK_WORDS;
    char*                tail    = (char*)d_ws + (size_t)(1 + qpb) * MASK_WORDS * 4;
    unsigned long long*  acc64   = (unsigned long long*)tail;
    unsigned int*        cnt     = (unsigned int*)(tail + 8);

    tbit_kernel<<<1024, 256, 0, stream>>>(targets, tbits_g, acc64, cnt);

    dim3 g1(qpb, NB);
    switch (qpb) {
        case 8:
            gt_kernel<8><<<g1, 512, 0, stream>>>(paths_w, tbits_g, pmask);
            loss_kernel<8><<<LOSS_BLOCKS, 256, 0, stream>>>(preds, pmask, acc64, cnt, out);
            break;
        case 4:
            gt_kernel<4><<<g1, 512, 0, stream>>>(paths_w, tbits_g, pmask);
            loss_kernel<4><<<LOSS_BLOCKS, 256, 0, stream>>>(preds, pmask, acc64, cnt, out);
            break;
        default:
            gt_kernel<2><<<g1, 512, 0, stream>>>(paths_w, tbits_g, pmask);
            loss_kernel<2><<<LOSS_BLOCKS, 256, 0, stream>>>(preds, pmask, acc64, cnt, out);
            break;
    }
}

// Round 9
// 33.836 us; speedup vs baseline: 1.8861x; 1.7679x over previous
//
#include <hip/hip_runtime.h>

// Problem constants (fixed by the reference's setup_inputs):
//   B=128 batches, S=32768 sequence, P=65536 path steps.
#define NB 128
#define NS 32768
#define NP 65536
#define POS_W 5.0f

constexpr int MASK_WORDS = (NB * NS) / 32;   // 131072 words = 512 KB per mask plane
constexpr int WPB        = NS / 32;          // 1024 mask words per batch (4 KB)
constexpr int LOSS_BLOCKS = 1024;

// ws layout:
//   [0, MASK_WORDS*4)                     : global targets bitmap (tbits)
//   [MASK_WORDS*4, +QPB*MASK_WORDS*4)     : QPB partial gt-mask planes
//   [after planes]                        : per-block loss partials (4 KB)
//
// NOTE (journal): no hipMemsetAsync for small regions (R7: tiny fill dispatch
// in the graph), and NO device-scope __threadfence fan-in reduction (R8: 1024
// staggered L2-invalidating fences cost ~25 us by evicting other blocks'
// streams). Fence-free partials + 1-block final is the proven-fast shape.

// ---------------------------------------------------------------------------
// One-shot: targets (16 MB int32) -> 512 KB bitmap, via per-wave ballot.
__global__ __launch_bounds__(256)
void tbit_kernel(const int* __restrict__ targets, unsigned int* __restrict__ tb) {
    constexpr int NSEG = NB * NS / 64;
    const int lane = threadIdx.x & 63;
    const int wid  = (blockIdx.x * blockDim.x + threadIdx.x) >> 6;
    const int nw   = (gridDim.x * blockDim.x) >> 6;
    for (int s = wid; s < NSEG; s += nw) {
        const unsigned long long m = __ballot(targets[(size_t)s * 64 + lane] != 0);
        if (lane == 0)       tb[s * 2]     = (unsigned int)m;
        else if (lane == 32) tb[s * 2 + 1] = (unsigned int)(m >> 32);
    }
}

// ---------------------------------------------------------------------------
// One block = (batch b, plane q), 512 threads. Lane-consecutive (coalesced)
// int4 loads, ALL iterations hoisted into registers (deep MLP). prev-pj via
// shfl; per-wave boundary values prefetched by lanes 0..NIT-1 before the loop
// (no divergent loads inside). Random accesses stay in LDS (ds_or atomics).
template <int QPB>
__global__ __launch_bounds__(512)
void gt_kernel(const int* __restrict__ pw, const unsigned int* __restrict__ tbits_g,
               unsigned int* __restrict__ pmask) {
    __shared__ unsigned int tbits[WPB];   // 4 KB: targets[b] as bits
    __shared__ unsigned int gbits[WPB];   // 4 KB: this block's gt-bit plane

    // Layout detect (uniform scalar): int64 -> hi word of last elem == 0.
    const int is64 = (pw[2 * (size_t)NP - 1] == 0);

    const int q    = blockIdx.x;
    const int b    = blockIdx.y;
    const int tid  = threadIdx.x;         // 0..511
    const int lane = tid & 63;
    const int wbase = tid & ~63;          // wave's base tid

    tbits[tid]       = tbits_g[(size_t)b * WPB + tid];
    tbits[tid + 512] = tbits_g[(size_t)b * WPB + tid + 512];
    gbits[tid]       = 0u;
    gbits[tid + 512] = 0u;
    __syncthreads();

    constexpr int STEPS = NP / QPB;              // steps per block (8192 @ QPB=8)
    const int    k0    = q * STEPS;              // batch-local base step
    const size_t sbase = (size_t)b * NP + k0;    // global base step
    const int4*  p4    = (const int4*)pw;

    if (!is64) {
        // int32 layout: one int4 = 2 pairs; iter it: thread's steps are
        // k = k0 + (it*512 + tid)*2, k+1.  Lane-consecutive -> coalesced.
        constexpr int NIT = STEPS / 1024;        // 8 @ QPB=8
        constexpr int NCH = (NIT + 7) / 8;
        const size_t pb = sbase >> 1;
        // Per-wave boundary values: lane l holds prev-pj for iteration l.
        int bval = -1;
        if (lane < NIT) {
            const int kf = k0 + (lane * 512 + wbase) * 2;
            if (kf != 0) bval = pw[2 * ((size_t)b * NP + kf) - 1];
        }
        #pragma unroll
        for (int ch = 0; ch < NCH; ++ch) {
            int4 a[8];
            #pragma unroll
            for (int j = 0; j < 8; ++j) a[j] = p4[pb + (ch * 8 + j) * 512 + tid];
            #pragma unroll
            for (int j = 0; j < 8; ++j) {
                const int it = ch * 8 + j;
                const int pi0 = a[j].x, pj0 = a[j].y, pi1 = a[j].z, pj1 = a[j].w;
                const int pl = __shfl_up(pj1, 1);
                const int bv = __shfl(bval, it);
                const int prev = (lane == 0) ? bv : pl;
                const bool f0 = (pj0 != prev);
                const bool f1 = (pj1 != pj0);
                if (f0 && ((tbits[pj0 >> 5] >> (pj0 & 31)) & 1u))
                    atomicOr(&gbits[pi0 >> 5], 1u << (pi0 & 31));
                if (f1 && ((tbits[pj1 >> 5] >> (pj1 & 31)) & 1u))
                    atomicOr(&gbits[pi1 >> 5], 1u << (pi1 & 31));
            }
        }
    } else {
        // int64 layout: one int4 = 1 pair (pi=x, pj=z); iter it: step
        // k = k0 + it*512 + tid.  Lane-consecutive -> coalesced.
        constexpr int NIT = STEPS / 512;         // 16 @ QPB=8
        constexpr int NCH = (NIT + 7) / 8;
        int bval = -1;
        if (lane < NIT) {
            const int kf = k0 + lane * 512 + wbase;
            if (kf != 0) bval = pw[4 * ((size_t)b * NP + kf) - 2];
        }
        #pragma unroll
        for (int ch = 0; ch < NCH; ++ch) {
            int4 a[8];
            #pragma unroll
            for (int j = 0; j < 8; ++j) a[j] = p4[sbase + (ch * 8 + j) * 512 + tid];
            #pragma unroll
            for (int j = 0; j < 8; ++j) {
                const int it = ch * 8 + j;
                const int pi = a[j].x, pj = a[j].z;
                const int pl = __shfl_up(pj, 1);
                const int bv = __shfl(bval, it);
                const int prev = (lane == 0) ? bv : pl;
                if ((pj != prev) && ((tbits[pj >> 5] >> (pj & 31)) & 1u))
                    atomicOr(&gbits[pi >> 5], 1u << (pi & 31));
            }
        }
    }
    __syncthreads();

    unsigned int* dst = pmask + (size_t)q * MASK_WORDS + (size_t)b * WPB;
    dst[tid]       = gbits[tid];
    dst[tid + 512] = gbits[tid + 512];
}

// ---------------------------------------------------------------------------
// Streaming loss, float4-vectorized; gt bit = OR of QPB partial planes
// (unrolled -> independent loads). Fence-free deterministic partials.
template <int QPB>
__global__ __launch_bounds__(256)
void loss_kernel(const float* __restrict__ preds, const unsigned int* __restrict__ pmask,
                 float* __restrict__ partials) {
    constexpr int N4 = (NB * NS) / 4;   // 1,048,576 float4s
    float acc = 0.f;
    const int stride = gridDim.x * blockDim.x;
    for (int idx = blockIdx.x * blockDim.x + threadIdx.x; idx < N4; idx += stride) {
        const float4 x = reinterpret_cast<const float4*>(preds)[idx];
        unsigned int mw = 0u;
        #pragma unroll
        for (int q = 0; q < QPB; ++q)
            mw |= pmask[(size_t)q * MASK_WORDS + (idx >> 3)];
        const unsigned int m = mw >> ((idx & 7) * 4);
        const float xs[4] = {x.x, x.y, x.z, x.w};
#pragma unroll
        for (int j = 0; j < 4; ++j) {
            const float v = xs[j];
            // stable softplus: sp(v) = log(1+exp(-|v|)) + max(v,0);  sp(-v) = sp(v) - v
            const float t = __logf(1.f + __expf(-fabsf(v)));
            const float sp_pos = t + fmaxf(v, 0.f);
            const float sp_neg = sp_pos - v;
            acc += ((m >> j) & 1u) ? POS_W * sp_neg : sp_pos;
        }
    }
    for (int off = 32; off; off >>= 1) acc += __shfl_down(acc, off);
    __shared__ float sacc[4];
    const int wave = threadIdx.x >> 6, lane = threadIdx.x & 63;
    if (lane == 0) sacc[wave] = acc;
    __syncthreads();
    if (threadIdx.x == 0) {
        float s = 0.f;
#pragma unroll
        for (int w = 0; w < 4; ++w) s += sacc[w];
        partials[blockIdx.x] = s;
    }
}

// ---------------------------------------------------------------------------
__global__ __launch_bounds__(256)
void final_kernel(const float* __restrict__ partials, float* __restrict__ out) {
    float acc = 0.f;
    for (int i = threadIdx.x; i < LOSS_BLOCKS; i += 256) acc += partials[i];
    for (int off = 32; off; off >>= 1) acc += __shfl_down(acc, off);
    __shared__ float sacc[4];
    const int wave = threadIdx.x >> 6, lane = threadIdx.x & 63;
    if (lane == 0) sacc[wave] = acc;
    __syncthreads();
    if (threadIdx.x == 0) {
        float s = 0.f;
#pragma unroll
        for (int w = 0; w < 4; ++w) s += sacc[w];
        out[0] = s * (1.0f / ((float)NB * (float)NS));
    }
}

// ---------------------------------------------------------------------------
extern "C" void kernel_launch(void* const* d_in, const int* in_sizes, int n_in,
                              void* d_out, int out_size, void* d_ws, size_t ws_size,
                              hipStream_t stream) {
    const float* preds   = (const float*)d_in[0];
    const int*   targets = (const int*)d_in[1];
    const int*   paths_w = (const int*)d_in[2];   // int32 words; layout auto-detected
    float*       out     = (float*)d_out;

    // Pick planes-per-batch by available workspace (deterministic for fixed ws).
    int qpb = 8;
    while (qpb > 2 &&
           ws_size < (size_t)(1 + qpb) * MASK_WORDS * 4 + (size_t)LOSS_BLOCKS * 4)
        qpb >>= 1;

    unsigned int* tbits_g  = (unsigned int*)d_ws;
    unsigned int* pmask    = tbits_g + MASK_WORDS;
    float*        partials = (float*)((char*)d_ws +
                              (size_t)(1 + qpb) * MASK_WORDS * 4);

    tbit_kernel<<<1024, 256, 0, stream>>>(targets, tbits_g);

    dim3 g1(qpb, NB);
    switch (qpb) {
        case 8:
            gt_kernel<8><<<g1, 512, 0, stream>>>(paths_w, tbits_g, pmask);
            loss_kernel<8><<<LOSS_BLOCKS, 256, 0, stream>>>(preds, pmask, partials);
            break;
        case 4:
            gt_kernel<4><<<g1, 512, 0, stream>>>(paths_w, tbits_g, pmask);
            loss_kernel<4><<<LOSS_BLOCKS, 256, 0, stream>>>(preds, pmask, partials);
            break;
        default:
            gt_kernel<2><<<g1, 512, 0, stream>>>(paths_w, tbits_g, pmask);
            loss_kernel<2><<<LOSS_BLOCKS, 256, 0, stream>>>(preds, pmask, partials);
            break;
    }

    final_kernel<<<1, 256, 0, stream>>>(partials, out);
}